// Round 14
// baseline (199.508 us; speedup 1.0000x reference)
//
#include <hip/hip_runtime.h>

#define N_VEC 131072   // B*H*W
#define DIM   64
#define KCODE 1024
#define HW    4096
#define DHW   262144
#define EPS   0.125f   // near-tie margin (validated r4-r8)
#define WLCAP 8192     // count ~3700 observed; 2.2x headroom
#define BLK_ROWS 128   // rows per block; 4 waves x 32 rows
#define PITCH 72       // shorts per LDS row (144 B)
#define BCHUNK 64      // main: codes per LDS-staged codebook chunk
#define NBCHUNK 16
#define RB_VEC 4       // rescue: vectors per block-iteration
#define RGRID 1024     // rescue grid

typedef short short8 __attribute__((ext_vector_type(8)));
typedef float f32x4  __attribute__((ext_vector_type(4)));

// ws layout (bytes) -- proven 401408 footprint:
//   0      : double loss accumulator
//   8      : int flagged counter
//   12     : int done-ticket counter (unused now)
//   64     : norms f32[1024]
//   8192   : eh  bf16-bits short[65536]
//   139264 : el  bf16-bits short[65536]
//   270336 : worklist int[WLCAP]          (ends 303104)
//   303104 : lsum f64[RGRID]              (8 KB, ends 311296)

__device__ __forceinline__ unsigned short f32_to_bf16_rne(float x) {
    unsigned u = __float_as_uint(x);
    u += 0x7FFFu + ((u >> 16) & 1u);
    return (unsigned short)(u >> 16);
}
__device__ __forceinline__ float bf16_to_f32(unsigned short h) {
    return __uint_as_float((unsigned)h << 16);
}

__global__ __launch_bounds__(256) void vq_prep(
    const float* __restrict__ cb, float* __restrict__ norms,
    short* __restrict__ ehg, short* __restrict__ elg,
    double* __restrict__ loss_acc, int* __restrict__ counter,
    int* __restrict__ done)
{
    const int t = threadIdx.x;
    if (blockIdx.x == 0 && t == 0) { *loss_acc = 0.0; *counter = 0; *done = 0; }

    const int k    = blockIdx.x * 16 + (t >> 4);
    const int part = t & 15;
    const float4 v = *(const float4*)(cb + k * DIM + part * 4);

    float s = 0.f;
    s = fmaf(v.x, v.x, s); s = fmaf(v.y, v.y, s);
    s = fmaf(v.z, v.z, s); s = fmaf(v.w, v.w, s);
    #pragma unroll
    for (int m = 1; m <= 8; m <<= 1) s += __shfl_xor(s, m, 64);
    if (part == 0) norms[k] = s;

    short h[4], l[4];
    const float vv[4] = { v.x, v.y, v.z, v.w };
    #pragma unroll
    for (int j = 0; j < 4; ++j) {
        unsigned short hh = f32_to_bf16_rne(vv[j]);
        unsigned short ll = f32_to_bf16_rne(vv[j] - bf16_to_f32(hh));
        h[j] = (short)hh; l[j] = (short)ll;
    }
    *(short4*)(ehg + k * DIM + part * 4) = make_short4(h[0], h[1], h[2], h[3]);
    *(short4*)(elg + k * DIM + part * 4) = make_short4(l[0], l[1], l[2], l[3]);
}

// Main v7 = v6 structure with an LDS diet: 79.4 KB -> ~42 KB -> 3 blocks/CU.
// R13 counters showed main co-issue-correct (VALU 42% : MFMA 26% matches the
// static instruction ratio) but both pipes idle ~55%: 2 blocks/CU could not
// cover barrier drains + LDS latency. Changes:
// - zh/zl (36,864 B, dead after A-frag extraction) and the 4 chunk buffers
//   (exactly 36,864 B) now SHARE one smem region; one added barrier between
//   A-frag reads and the chunk-0 write covers the overwrite hazard.
// - epilogue re-reads z from global (coalesced, block slice is L2-hot from
//   staging); loss now uses exact f32 z (closer to reference than the bf16
//   reconstruction).
// - __launch_bounds__(256, 3).
__global__ __launch_bounds__(256, 3) void vq_main(
    const float* __restrict__ z, const float* __restrict__ cb,
    const float* __restrict__ norms, const short* __restrict__ ehg,
    const short* __restrict__ elg, float* __restrict__ out,
    double* __restrict__ loss_acc, int* __restrict__ counter,
    int* __restrict__ worklist, int cap)
{
    __shared__ short  smem[18432];            // 36,864 B, two-phase union:
                                              //  stage:  zh[9216] | zl[9216]
                                              //  k-loop: ebh0|ebh1|ebl0|ebl1 (4608 each)
    __shared__ float  nsh[KCODE];             // norms, block-resident
    __shared__ int    kidx[BLK_ROWS];
    __shared__ float  wsum[4];
    __shared__ int    blkrows[BLK_ROWS];      // flagged row-local ids
    __shared__ int    blkcnt;
    __shared__ int    blkbase;

    short* const zh   = smem;                 // [128][72]
    short* const zl   = smem + 9216;
    short* const ebh0 = smem;                 // [64][72] each
    short* const ebh1 = smem + 4608;
    short* const ebl0 = smem + 9216;
    short* const ebl1 = smem + 13824;

    const int t   = threadIdx.x;              // 0..255
    const int n0  = blockIdx.x * BLK_ROWS;
    const int b   = n0 >> 12;
    const int hw0 = n0 & 4095;

    const int lane = t & 63;
    const int wave = t >> 6;                  // 0..3
    const int l15  = lane & 15;
    const int quad = lane >> 4;
    const int rowbase = wave * 32;            // 2 row-tiles per wave

    if (t == 0) blkcnt = 0;

    // ---- stage z -> LDS (8 float4/thread, register transpose, b128 writes) ----
    {
        const int hwl   = (t & 31) * 4;       // 4 consecutive rows
        const int dbase = (t >> 5) * 8;       // 8 consecutive d
        float4 v[8];
        #pragma unroll
        for (int p = 0; p < 8; ++p)
            v[p] = *(const float4*)(z + (size_t)b * DHW + (size_t)(dbase + p) * HW + hw0 + hwl);
        #pragma unroll
        for (int c = 0; c < 4; ++c) {
            short8 hi, lo;
            #pragma unroll
            for (int p = 0; p < 8; ++p) {
                const float* vp = (const float*)&v[p];
                float f = -2.0f * vp[c];
                unsigned short hh = f32_to_bf16_rne(f);
                unsigned short ll = f32_to_bf16_rne(f - bf16_to_f32(hh));
                hi[p] = (short)hh; lo[p] = (short)ll;
            }
            *(short8*)&zh[(hwl + c) * PITCH + dbase] = hi;
            *(short8*)&zl[(hwl + c) * PITCH + dbase] = lo;
        }
    }

    // ---- stage norms -> LDS ----
    #pragma unroll
    for (int j = 0; j < 4; ++j) nsh[t + j * 256] = norms[t + j * 256];

    // ---- B-staging prologue: thread owns 32 B hi + 32 B lo per chunk ----
    const int cc = t >> 2;                    // code within chunk (0..63)
    const int pp = (t & 3) * 16;              // short offset within code row
    short8 pf0[4], pf1[4];                    // [0..1]=hi, [2..3]=lo
    #pragma unroll
    for (int j = 0; j < 2; ++j) {
        pf0[j]     = *(const short8*)(ehg + (size_t)cc * DIM + pp + j * 8);
        pf0[2 + j] = *(const short8*)(elg + (size_t)cc * DIM + pp + j * 8);
        pf1[j]     = *(const short8*)(ehg + (size_t)(BCHUNK + cc) * DIM + pp + j * 8);
        pf1[2 + j] = *(const short8*)(elg + (size_t)(BCHUNK + cc) * DIM + pp + j * 8);
    }
    __syncthreads();                          // z + norms ready

    // ---- A-fragments (32 VGPRs, resident) ----
    short8 a_h[2][2], a_l[2][2];
    #pragma unroll
    for (int rt = 0; rt < 2; ++rt)
        #pragma unroll
        for (int kt = 0; kt < 2; ++kt) {
            const int idx = (rowbase + rt * 16 + l15) * PITCH + kt * 32 + quad * 8;
            a_h[rt][kt] = *(const short8*)&zh[idx];
            a_l[rt][kt] = *(const short8*)&zl[idx];
        }
    __syncthreads();                          // A-frag reads done before overwrite

    // ---- write chunk 0 into buf0 (overwrites the dead z-tile region) ----
    #pragma unroll
    for (int j = 0; j < 2; ++j) {
        *(short8*)&ebh0[cc * PITCH + pp + j * 8] = pf0[j];
        *(short8*)&ebl0[cc * PITCH + pp + j * 8] = pf0[2 + j];
    }
    __syncthreads();                          // buf0 ready

    float best[2][4], best2[2][4];
    #pragma unroll
    for (int rt = 0; rt < 2; ++rt)
        #pragma unroll
        for (int r = 0; r < 4; ++r) { best[rt][r] = 3.0e38f; best2[rt][r] = 3.0e38f; }

    // chunk body: issue ch+2 loads -> pfL; compute chunk ch from (bhR,blR);
    // write pfW (chunk ch+1) -> (bhW,blW); barrier.
    auto body = [&](int ch, const short* bhR, const short* blR,
                    short* bhW, short* blW, short8 (&pfL)[4], short8 (&pfW)[4]) {
        if (ch + 2 < NBCHUNK) {
            const size_t gb = (size_t)((ch + 2) * BCHUNK + cc) * DIM + pp;
            #pragma unroll
            for (int j = 0; j < 2; ++j) {
                pfL[j]     = *(const short8*)(ehg + gb + j * 8);
                pfL[2 + j] = *(const short8*)(elg + gb + j * 8);
            }
        }
        // hoist the 4 norm reads (they gate each MFMA chain's acc init)
        float nrm4[4];
        #pragma unroll
        for (int ct = 0; ct < 4; ++ct) nrm4[ct] = nsh[ch * BCHUNK + ct * 16 + l15];

        #pragma unroll
        for (int ct = 0; ct < 4; ++ct) {
            const int crow = ct * 16 + l15;
            short8 Bh0 = *(const short8*)&bhR[crow * PITCH + quad * 8];
            short8 Bh1 = *(const short8*)&bhR[crow * PITCH + 32 + quad * 8];
            short8 Bl0 = *(const short8*)&blR[crow * PITCH + quad * 8];
            short8 Bl1 = *(const short8*)&blR[crow * PITCH + 32 + quad * 8];
            const unsigned colbits = (unsigned)(ch * BCHUNK + crow);
            const float nrm = nrm4[ct];
            #pragma unroll
            for (int rt = 0; rt < 2; ++rt) {
                f32x4 acc = { nrm, nrm, nrm, nrm };
                acc = __builtin_amdgcn_mfma_f32_16x16x32_bf16(a_h[rt][0], Bh0, acc, 0, 0, 0);
                acc = __builtin_amdgcn_mfma_f32_16x16x32_bf16(a_h[rt][1], Bh1, acc, 0, 0, 0);
                acc = __builtin_amdgcn_mfma_f32_16x16x32_bf16(a_h[rt][0], Bl0, acc, 0, 0, 0);
                acc = __builtin_amdgcn_mfma_f32_16x16x32_bf16(a_h[rt][1], Bl1, acc, 0, 0, 0);
                acc = __builtin_amdgcn_mfma_f32_16x16x32_bf16(a_l[rt][0], Bh0, acc, 0, 0, 0);
                acc = __builtin_amdgcn_mfma_f32_16x16x32_bf16(a_l[rt][1], Bh1, acc, 0, 0, 0);
                #pragma unroll
                for (int r = 0; r < 4; ++r) {
                    float p = __uint_as_float((__float_as_uint(acc[r]) & 0xFFFFFC00u) | colbits);
                    best2[rt][r] = fminf(best2[rt][r], fmaxf(best[rt][r], p));
                    best[rt][r]  = fminf(best[rt][r], p);
                }
            }
        }
        if (ch + 1 < NBCHUNK) {
            #pragma unroll
            for (int j = 0; j < 2; ++j) {
                *(short8*)&bhW[cc * PITCH + pp + j * 8] = pfW[j];
                *(short8*)&blW[cc * PITCH + pp + j * 8] = pfW[2 + j];
            }
        }
        __syncthreads();
    };

    for (int chp = 0; chp < 8; ++chp) {
        body(2 * chp,     ebh0, ebl0, ebh1, ebl1, pf0, pf1);
        body(2 * chp + 1, ebh1, ebl1, ebh0, ebl0, pf1, pf0);
    }

    // ---- merge across 16 code-lanes; each wave has complete top-2 for its rows ----
    #pragma unroll
    for (int rt = 0; rt < 2; ++rt)
        #pragma unroll
        for (int r = 0; r < 4; ++r) {
            float bb = best[rt][r], b2 = best2[rt][r];
            #pragma unroll
            for (int m = 1; m <= 8; m <<= 1) {
                float ob  = __shfl_xor(bb, m, 64);
                float ob2 = __shfl_xor(b2, m, 64);
                b2 = fminf(fminf(b2, ob2), fmaxf(bb, ob));
                bb = fminf(bb, ob);
            }
            best[rt][r] = bb; best2[rt][r] = b2;
        }

    // ---- per-row result: flags into LDS list (LDS atomics only) ----
    if (l15 == 0) {
        #pragma unroll
        for (int rt = 0; rt < 2; ++rt)
            #pragma unroll
            for (int r = 0; r < 4; ++r) {
                unsigned ub = __float_as_uint(best[rt][r]);
                int k = (int)(ub & 1023u);
                float sb  = __uint_as_float(ub & 0xFFFFFC00u);
                float sb2 = __uint_as_float(__float_as_uint(best2[rt][r]) & 0xFFFFFC00u);
                int rowl = rowbase + rt * 16 + quad * 4 + r;
                int flag = 0;
                if (sb2 - sb < EPS) {
                    int p = atomicAdd(&blkcnt, 1);   // LDS atomic, per-CU fast
                    blkrows[p] = rowl; flag = 1;
                }
                kidx[rowl] = k | (flag << 15);
            }
    }
    __syncthreads();
    // ---- ONE global atomic per block reserves the slot range ----
    if (t == 0) blkbase = (blkcnt > 0) ? atomicAdd(counter, blkcnt) : 0;
    __syncthreads();
    if (t < blkcnt) {
        const int rowl = blkrows[t];
        const int slot = blkbase + t;
        if (slot < cap) worklist[slot] = n0 + rowl;
        else            kidx[rowl] &= 0x7FFF;   // overflow: un-flag, epilogue handles
    }
    __syncthreads();

    // ---- epilogue: row = t&127, dgrp = t>>7 covers 32 d; coalesced stores.
    //      z re-read from global (block slice L2-hot from staging); exact f32. ----
    float lsum = 0.f;
    {
        const int row  = t & 127;
        const int d0   = (t >> 7) * 32;
        const int ki   = kidx[row];
        const int k    = ki & 1023;
        const int flag = (ki >> 15) & 1;
        if (!flag) {
            const float4* cbr = (const float4*)(cb + k * DIM + d0);
            const float*  zp  = z   + (size_t)b * DHW + (size_t)d0 * HW + hw0 + row;
            float*        op  = out + (size_t)b * DHW + (size_t)d0 * HW + hw0 + row;
            #pragma unroll
            for (int g = 0; g < 4; ++g) {
                float4 e0 = cbr[2 * g];
                float4 e1 = cbr[2 * g + 1];
                const float ev[8] = { e0.x, e0.y, e0.z, e0.w, e1.x, e1.y, e1.z, e1.w };
                #pragma unroll
                for (int j = 0; j < 8; ++j) {
                    const size_t off = (size_t)(g * 8 + j) * HW;
                    float zv = zp[off];
                    op[off] = ev[j];
                    float df = ev[j] - zv;
                    lsum = fmaf(df, df, lsum);
                }
            }
        }
    }
    #pragma unroll
    for (int off = 32; off > 0; off >>= 1) lsum += __shfl_down(lsum, off, 64);
    if (lane == 0) wsum[wave] = lsum;
    __syncthreads();
    if (t == 0)
        atomicAdd(loss_acc, (double)((wsum[0] + wsum[1]) + (wsum[2] + wsum[3])));
}

// Rescue v10 (unchanged from R13): 4 vectors per block-iteration, cb row reads
// amortized over 4 dot products; row loop unroll 1, q loop unroll 4; per-block
// loss slot write + stream-ordered finalize (zero same-address RMWs).
__global__ __launch_bounds__(256) void vq_rescue(
    const float* __restrict__ z, const float* __restrict__ cb,
    float* __restrict__ out,
    const int* __restrict__ counter, const int* __restrict__ worklist, int cap,
    double* __restrict__ lsum_ws)
{
    __shared__ float zsh[RB_VEC][DIM];           // 4 z rows
    __shared__ unsigned long long pls[4][RB_VEC];
    __shared__ double dsum[4];
    __shared__ int    nwl[RB_VEC];

    int count = *counter; if (count > cap) count = cap;
    const int t    = threadIdx.x;
    const int wave = t >> 6;
    const int lane = t & 63;

    double lloss = 0.0;                          // per-wave (lane0) accumulator

    for (int base = blockIdx.x * RB_VEC; base < count; base += gridDim.x * RB_VEC) {
        // ---- wave w stages z row of vector w (scattered, 1 load/thread) ----
        {
            const int i = base + wave;
            int n = -1; float zval = 0.f;
            if (i < count) {
                n = worklist[i];
                const int bb = n >> 12, hw = n & 4095;
                zval = z[(size_t)bb * DHW + (size_t)lane * HW + hw];
            }
            zsh[wave][lane] = zval;
            if (lane == 0) nwl[wave] = n;
        }
        __syncthreads();                         // all 4 z rows visible

        // ---- ||z||^2 per vector (shuffle reduce; inactive vectors -> 0) ----
        double zn[RB_VEC];
        #pragma unroll
        for (int v = 0; v < RB_VEC; ++v) {
            const float zl = zsh[v][lane];
            double s = (double)zl * (double)zl;
            #pragma unroll
            for (int m = 1; m <= 32; m <<= 1) s += __shfl_xor(s, m, 64);
            zn[v] = s;
        }

        unsigned long long best[RB_VEC];
        #pragma unroll
        for (int v = 0; v < RB_VEC; ++v) best[v] = ~0ull;

        #pragma unroll 1
        for (int r = 0; r < 4; ++r) {
            const int k = wave * 256 + r * 64 + lane;
            const float4* cr = (const float4*)(cb + (size_t)k * DIM);
            double nj0 = 0.0, nj1 = 0.0;
            double dt[RB_VEC];
            #pragma unroll
            for (int v = 0; v < RB_VEC; ++v) dt[v] = 0.0;
            #pragma unroll 4
            for (int q = 0; q < 16; ++q) {
                const float4 c = cr[q];
                nj0 = fma((double)c.x, (double)c.x, nj0);
                nj1 = fma((double)c.y, (double)c.y, nj1);
                nj0 = fma((double)c.z, (double)c.z, nj0);
                nj1 = fma((double)c.w, (double)c.w, nj1);
                #pragma unroll
                for (int v = 0; v < RB_VEC; ++v) {
                    const float4 zv = *(const float4*)&zsh[v][q * 4];
                    dt[v] = fma((double)c.x, (double)zv.x, dt[v]);
                    dt[v] = fma((double)c.y, (double)zv.y, dt[v]);
                    dt[v] = fma((double)c.z, (double)zv.z, dt[v]);
                    dt[v] = fma((double)c.w, (double)zv.w, dt[v]);
                }
            }
            const double nj = nj0 + nj1;
            #pragma unroll
            for (int v = 0; v < RB_VEC; ++v) {
                const double p = fmax(fma(-2.0, dt[v], nj) + zn[v], 0.0);
                const unsigned long long q64 =
                    ((unsigned long long)__double_as_longlong(p) & ~1023ull)
                    | (unsigned long long)k;
                if (q64 < best[v]) best[v] = q64;
            }
        }

        // ---- cross-lane min per vector ----
        #pragma unroll
        for (int v = 0; v < RB_VEC; ++v) {
            unsigned long long b = best[v];
            #pragma unroll
            for (int m = 1; m <= 32; m <<= 1) {
                unsigned long long o = __shfl_xor(b, m, 64);
                if (o < b) b = o;
            }
            if (lane == 0) pls[wave][v] = b;
        }
        __syncthreads();                         // partials visible

        // ---- wave w finalizes vector w ----
        {
            const int n = nwl[wave];
            if (n >= 0) {
                unsigned long long p0 = pls[0][wave], p1 = pls[1][wave];
                unsigned long long p2 = pls[2][wave], p3 = pls[3][wave];
                unsigned long long p = p0 < p1 ? p0 : p1;
                if (p2 < p) p = p2;
                if (p3 < p) p = p3;
                const int bk = (int)(p & 1023ull);
                const int bb = n >> 12, hw = n & 4095;
                out[(size_t)bb * DHW + (size_t)lane * HW + hw] = cb[(size_t)bk * DIM + lane];
                if (lane == 0)
                    lloss += __longlong_as_double((long long)(p & ~1023ull));
            }
        }
        __syncthreads();                         // zsh/pls safe to overwrite
    }

    if (lane == 0) dsum[wave] = lloss;
    __syncthreads();
    if (t == 0)
        lsum_ws[blockIdx.x] = (dsum[0] + dsum[1]) + (dsum[2] + dsum[3]);
}

// Stream-ordered finalize: reduce the RGRID block partials + main's loss_acc.
__global__ __launch_bounds__(256) void vq_finalize(
    const double* __restrict__ lsum_ws, const double* __restrict__ loss_acc,
    float* __restrict__ loss_out)
{
    __shared__ double ws4[4];
    const int t = threadIdx.x;
    double s = 0.0;
    for (int j = t; j < RGRID; j += 256) s += lsum_ws[j];
    #pragma unroll
    for (int m = 1; m <= 32; m <<= 1) s += __shfl_xor(s, m, 64);
    if ((t & 63) == 0) ws4[t >> 6] = s;
    __syncthreads();
    if (t == 0) {
        double total = *loss_acc + ((ws4[0] + ws4[1]) + (ws4[2] + ws4[3]));
        *loss_out = (float)(1.25 * total * (1.0 / (double)((long)N_VEC * DIM)));
    }
}

extern "C" void kernel_launch(void* const* d_in, const int* in_sizes, int n_in,
                              void* d_out, int out_size, void* d_ws, size_t ws_size,
                              hipStream_t stream) {
    const float* z  = (const float*)d_in[0];
    const float* cb = (const float*)d_in[1];
    float* out      = (float*)d_out;
    char*  ws       = (char*)d_ws;

    double* loss_acc = (double*)ws;
    int*    counter  = (int*)(ws + 8);
    int*    done     = (int*)(ws + 12);
    float*  norms    = (float*)(ws + 64);
    short*  ehg      = (short*)(ws + 8192);
    short*  elg      = (short*)(ws + 139264);
    int*    worklist = (int*)(ws + 270336);
    double* lsum_ws  = (double*)(ws + 303104);   // RGRID*8 = 8 KB, ends 311296

    int cap = WLCAP;
    long avail = ((long)ws_size - 270336) / 4;
    if (avail < cap) cap = (avail > 0) ? (int)avail : 0;

    vq_prep<<<dim3(KCODE / 16), dim3(256), 0, stream>>>(
        cb, norms, ehg, elg, loss_acc, counter, done);
    vq_main<<<dim3(N_VEC / BLK_ROWS), dim3(256), 0, stream>>>(
        z, cb, norms, ehg, elg, out, loss_acc, counter, worklist, cap);
    vq_rescue<<<dim3(RGRID), dim3(256), 0, stream>>>(
        z, cb, out, counter, worklist, cap, lsum_ws);
    vq_finalize<<<dim3(1), dim3(256), 0, stream>>>(
        lsum_ws, loss_acc, out + (out_size - 1));
}

// Round 15
// 184.667 us; speedup vs baseline: 1.0804x; 1.0804x over previous
//
#include <hip/hip_runtime.h>

#define N_VEC 131072   // B*H*W
#define DIM   64
#define KCODE 1024
#define HW    4096
#define DHW   262144
#define EPS   0.125f   // near-tie margin (validated r4-r8)
#define WLCAP 8192     // count ~3700 observed; 2.2x headroom
#define BLK_ROWS 128   // rows per block; 4 waves x 32 rows
#define PITCH 72       // shorts per LDS row (144 B)
#define BCHUNK 64      // main: codes per LDS-staged codebook chunk
#define NBCHUNK 16
#define RB_VEC 8       // rescue: vectors per block-iteration (2 per wave)
#define RGRID 1024     // rescue grid; single pass up to count=8192

typedef short short8 __attribute__((ext_vector_type(8)));
typedef float f32x4  __attribute__((ext_vector_type(4)));

// ws layout (bytes) -- proven 401408 footprint:
//   0      : double loss accumulator
//   8      : int flagged counter
//   12     : int done-ticket counter (unused now)
//   64     : norms f32[1024]
//   8192   : eh  bf16-bits short[65536]
//   139264 : el  bf16-bits short[65536]
//   270336 : worklist int[WLCAP]          (ends 303104)
//   303104 : lsum f64[RGRID]              (8 KB, ends 311296)

__device__ __forceinline__ unsigned short f32_to_bf16_rne(float x) {
    unsigned u = __float_as_uint(x);
    u += 0x7FFFu + ((u >> 16) & 1u);
    return (unsigned short)(u >> 16);
}
__device__ __forceinline__ float bf16_to_f32(unsigned short h) {
    return __uint_as_float((unsigned)h << 16);
}

__global__ __launch_bounds__(256) void vq_prep(
    const float* __restrict__ cb, float* __restrict__ norms,
    short* __restrict__ ehg, short* __restrict__ elg,
    double* __restrict__ loss_acc, int* __restrict__ counter,
    int* __restrict__ done)
{
    const int t = threadIdx.x;
    if (blockIdx.x == 0 && t == 0) { *loss_acc = 0.0; *counter = 0; *done = 0; }

    const int k    = blockIdx.x * 16 + (t >> 4);
    const int part = t & 15;
    const float4 v = *(const float4*)(cb + k * DIM + part * 4);

    float s = 0.f;
    s = fmaf(v.x, v.x, s); s = fmaf(v.y, v.y, s);
    s = fmaf(v.z, v.z, s); s = fmaf(v.w, v.w, s);
    #pragma unroll
    for (int m = 1; m <= 8; m <<= 1) s += __shfl_xor(s, m, 64);
    if (part == 0) norms[k] = s;

    short h[4], l[4];
    const float vv[4] = { v.x, v.y, v.z, v.w };
    #pragma unroll
    for (int j = 0; j < 4; ++j) {
        unsigned short hh = f32_to_bf16_rne(vv[j]);
        unsigned short ll = f32_to_bf16_rne(vv[j] - bf16_to_f32(hh));
        h[j] = (short)hh; l[j] = (short)ll;
    }
    *(short4*)(ehg + k * DIM + part * 4) = make_short4(h[0], h[1], h[2], h[3]);
    *(short4*)(elg + k * DIM + part * 4) = make_short4(l[0], l[1], l[2], l[3]);
}

// Main v6 (byte-identical to R13, the 80 us / 186 us-total best): LDS-staged B
// double-buffered, per-block LDS aggregation of worklist slots -> ONE global
// atomicAdd per block. R14's occupancy push (LDS union + epilogue-from-global)
// REGRESSED (+7.5 us main, +20 MB FETCH) -- occupancy was not the binding
// constraint; reverted.
__global__ __launch_bounds__(256, 2) void vq_main(
    const float* __restrict__ z, const float* __restrict__ cb,
    const float* __restrict__ norms, const short* __restrict__ ehg,
    const short* __restrict__ elg, float* __restrict__ out,
    double* __restrict__ loss_acc, int* __restrict__ counter,
    int* __restrict__ worklist, int cap)
{
    __shared__ short  zh[BLK_ROWS * PITCH];   // hi(-2z) bf16 bits, [row=hw][d]
    __shared__ short  zl[BLK_ROWS * PITCH];
    __shared__ short  ebh0[BCHUNK * PITCH];   // codebook chunk hi, double-buffered
    __shared__ short  ebh1[BCHUNK * PITCH];
    __shared__ short  ebl0[BCHUNK * PITCH];
    __shared__ short  ebl1[BCHUNK * PITCH];
    __shared__ float  nsh[KCODE];             // norms, block-resident
    __shared__ int    kidx[BLK_ROWS];
    __shared__ float  wsum[4];
    __shared__ int    blkrows[BLK_ROWS];      // flagged row-local ids
    __shared__ int    blkcnt;
    __shared__ int    blkbase;

    const int t   = threadIdx.x;              // 0..255
    const int n0  = blockIdx.x * BLK_ROWS;
    const int b   = n0 >> 12;
    const int hw0 = n0 & 4095;

    const int lane = t & 63;
    const int wave = t >> 6;                  // 0..3
    const int l15  = lane & 15;
    const int quad = lane >> 4;
    const int rowbase = wave * 32;            // 2 row-tiles per wave

    if (t == 0) blkcnt = 0;

    // ---- stage z -> LDS (8 float4/thread, register transpose, b128 writes) ----
    {
        const int hwl   = (t & 31) * 4;       // 4 consecutive rows
        const int dbase = (t >> 5) * 8;       // 8 consecutive d
        float4 v[8];
        #pragma unroll
        for (int p = 0; p < 8; ++p)
            v[p] = *(const float4*)(z + (size_t)b * DHW + (size_t)(dbase + p) * HW + hw0 + hwl);
        #pragma unroll
        for (int c = 0; c < 4; ++c) {
            short8 hi, lo;
            #pragma unroll
            for (int p = 0; p < 8; ++p) {
                const float* vp = (const float*)&v[p];
                float f = -2.0f * vp[c];
                unsigned short hh = f32_to_bf16_rne(f);
                unsigned short ll = f32_to_bf16_rne(f - bf16_to_f32(hh));
                hi[p] = (short)hh; lo[p] = (short)ll;
            }
            *(short8*)&zh[(hwl + c) * PITCH + dbase] = hi;
            *(short8*)&zl[(hwl + c) * PITCH + dbase] = lo;
        }
    }

    // ---- stage norms -> LDS ----
    #pragma unroll
    for (int j = 0; j < 4; ++j) nsh[t + j * 256] = norms[t + j * 256];

    // ---- B-staging prologue: thread owns 32 B hi + 32 B lo per chunk ----
    const int cc = t >> 2;                    // code within chunk (0..63)
    const int pp = (t & 3) * 16;              // short offset within code row
    short8 pf0[4], pf1[4];                    // [0..1]=hi, [2..3]=lo
    #pragma unroll
    for (int j = 0; j < 2; ++j) {
        pf0[j]     = *(const short8*)(ehg + (size_t)cc * DIM + pp + j * 8);
        pf0[2 + j] = *(const short8*)(elg + (size_t)cc * DIM + pp + j * 8);
        pf1[j]     = *(const short8*)(ehg + (size_t)(BCHUNK + cc) * DIM + pp + j * 8);
        pf1[2 + j] = *(const short8*)(elg + (size_t)(BCHUNK + cc) * DIM + pp + j * 8);
    }
    __syncthreads();                          // z + norms ready (prologue loads drain once)

    // ---- A-fragments (32 VGPRs, resident) ----
    short8 a_h[2][2], a_l[2][2];
    #pragma unroll
    for (int rt = 0; rt < 2; ++rt)
        #pragma unroll
        for (int kt = 0; kt < 2; ++kt) {
            const int idx = (rowbase + rt * 16 + l15) * PITCH + kt * 32 + quad * 8;
            a_h[rt][kt] = *(const short8*)&zh[idx];
            a_l[rt][kt] = *(const short8*)&zl[idx];
        }

    // ---- write chunk 0 into buf0 ----
    #pragma unroll
    for (int j = 0; j < 2; ++j) {
        *(short8*)&ebh0[cc * PITCH + pp + j * 8] = pf0[j];
        *(short8*)&ebl0[cc * PITCH + pp + j * 8] = pf0[2 + j];
    }
    __syncthreads();                          // buf0 ready

    float best[2][4], best2[2][4];
    #pragma unroll
    for (int rt = 0; rt < 2; ++rt)
        #pragma unroll
        for (int r = 0; r < 4; ++r) { best[rt][r] = 3.0e38f; best2[rt][r] = 3.0e38f; }

    // chunk body: issue ch+2 loads -> pfL; compute chunk ch from (bhR,blR);
    // write pfW (chunk ch+1) -> (bhW,blW); barrier.
    auto body = [&](int ch, const short* bhR, const short* blR,
                    short* bhW, short* blW, short8 (&pfL)[4], short8 (&pfW)[4]) {
        if (ch + 2 < NBCHUNK) {
            const size_t gb = (size_t)((ch + 2) * BCHUNK + cc) * DIM + pp;
            #pragma unroll
            for (int j = 0; j < 2; ++j) {
                pfL[j]     = *(const short8*)(ehg + gb + j * 8);
                pfL[2 + j] = *(const short8*)(elg + gb + j * 8);
            }
        }
        // hoist the 4 norm reads (they gate each MFMA chain's acc init)
        float nrm4[4];
        #pragma unroll
        for (int ct = 0; ct < 4; ++ct) nrm4[ct] = nsh[ch * BCHUNK + ct * 16 + l15];

        #pragma unroll
        for (int ct = 0; ct < 4; ++ct) {
            const int crow = ct * 16 + l15;
            short8 Bh0 = *(const short8*)&bhR[crow * PITCH + quad * 8];
            short8 Bh1 = *(const short8*)&bhR[crow * PITCH + 32 + quad * 8];
            short8 Bl0 = *(const short8*)&blR[crow * PITCH + quad * 8];
            short8 Bl1 = *(const short8*)&blR[crow * PITCH + 32 + quad * 8];
            const unsigned colbits = (unsigned)(ch * BCHUNK + crow);
            const float nrm = nrm4[ct];
            #pragma unroll
            for (int rt = 0; rt < 2; ++rt) {
                f32x4 acc = { nrm, nrm, nrm, nrm };
                acc = __builtin_amdgcn_mfma_f32_16x16x32_bf16(a_h[rt][0], Bh0, acc, 0, 0, 0);
                acc = __builtin_amdgcn_mfma_f32_16x16x32_bf16(a_h[rt][1], Bh1, acc, 0, 0, 0);
                acc = __builtin_amdgcn_mfma_f32_16x16x32_bf16(a_h[rt][0], Bl0, acc, 0, 0, 0);
                acc = __builtin_amdgcn_mfma_f32_16x16x32_bf16(a_h[rt][1], Bl1, acc, 0, 0, 0);
                acc = __builtin_amdgcn_mfma_f32_16x16x32_bf16(a_l[rt][0], Bh0, acc, 0, 0, 0);
                acc = __builtin_amdgcn_mfma_f32_16x16x32_bf16(a_l[rt][1], Bh1, acc, 0, 0, 0);
                #pragma unroll
                for (int r = 0; r < 4; ++r) {
                    float p = __uint_as_float((__float_as_uint(acc[r]) & 0xFFFFFC00u) | colbits);
                    best2[rt][r] = fminf(best2[rt][r], fmaxf(best[rt][r], p));
                    best[rt][r]  = fminf(best[rt][r], p);
                }
            }
        }
        if (ch + 1 < NBCHUNK) {
            #pragma unroll
            for (int j = 0; j < 2; ++j) {
                *(short8*)&bhW[cc * PITCH + pp + j * 8] = pfW[j];
                *(short8*)&blW[cc * PITCH + pp + j * 8] = pfW[2 + j];
            }
        }
        __syncthreads();
    };

    for (int chp = 0; chp < 8; ++chp) {
        body(2 * chp,     ebh0, ebl0, ebh1, ebl1, pf0, pf1);
        body(2 * chp + 1, ebh1, ebl1, ebh0, ebl0, pf1, pf0);
    }

    // ---- merge across 16 code-lanes; each wave has complete top-2 for its rows ----
    #pragma unroll
    for (int rt = 0; rt < 2; ++rt)
        #pragma unroll
        for (int r = 0; r < 4; ++r) {
            float bb = best[rt][r], b2 = best2[rt][r];
            #pragma unroll
            for (int m = 1; m <= 8; m <<= 1) {
                float ob  = __shfl_xor(bb, m, 64);
                float ob2 = __shfl_xor(b2, m, 64);
                b2 = fminf(fminf(b2, ob2), fmaxf(bb, ob));
                bb = fminf(bb, ob);
            }
            best[rt][r] = bb; best2[rt][r] = b2;
        }

    // ---- per-row result: flags into LDS list (LDS atomics only) ----
    if (l15 == 0) {
        #pragma unroll
        for (int rt = 0; rt < 2; ++rt)
            #pragma unroll
            for (int r = 0; r < 4; ++r) {
                unsigned ub = __float_as_uint(best[rt][r]);
                int k = (int)(ub & 1023u);
                float sb  = __uint_as_float(ub & 0xFFFFFC00u);
                float sb2 = __uint_as_float(__float_as_uint(best2[rt][r]) & 0xFFFFFC00u);
                int rowl = rowbase + rt * 16 + quad * 4 + r;
                int flag = 0;
                if (sb2 - sb < EPS) {
                    int p = atomicAdd(&blkcnt, 1);   // LDS atomic, per-CU fast
                    blkrows[p] = rowl; flag = 1;
                }
                kidx[rowl] = k | (flag << 15);
            }
    }
    __syncthreads();
    // ---- ONE global atomic per block reserves the slot range ----
    if (t == 0) blkbase = (blkcnt > 0) ? atomicAdd(counter, blkcnt) : 0;
    __syncthreads();
    if (t < blkcnt) {
        const int rowl = blkrows[t];
        const int slot = blkbase + t;
        if (slot < cap) worklist[slot] = n0 + rowl;
        else            kidx[rowl] &= 0x7FFF;   // overflow: un-flag, epilogue handles
    }
    __syncthreads();

    // ---- epilogue: row = t&127, dgrp = t>>7 covers 32 d; coalesced stores ----
    float lsum = 0.f;
    {
        const int row  = t & 127;
        const int d0   = (t >> 7) * 32;
        const int ki   = kidx[row];
        const int k    = ki & 1023;
        const int flag = (ki >> 15) & 1;
        if (!flag) {
            const float4* cbr = (const float4*)(cb + k * DIM + d0);
            const short8* zhr = (const short8*)&zh[row * PITCH + d0];
            const short8* zlr = (const short8*)&zl[row * PITCH + d0];
            float* op = out + (size_t)b * DHW + (size_t)d0 * HW + hw0 + row;
            #pragma unroll
            for (int g = 0; g < 4; ++g) {
                short8 hh = zhr[g];
                short8 ll = zlr[g];
                float4 e0 = cbr[2 * g];
                float4 e1 = cbr[2 * g + 1];
                const float ev[8] = { e0.x, e0.y, e0.z, e0.w, e1.x, e1.y, e1.z, e1.w };
                #pragma unroll
                for (int j = 0; j < 8; ++j) {
                    float zv = -0.5f * (bf16_to_f32((unsigned short)hh[j]) +
                                        bf16_to_f32((unsigned short)ll[j]));
                    op[(size_t)(g * 8 + j) * HW] = ev[j];
                    float df = ev[j] - zv;
                    lsum = fmaf(df, df, lsum);
                }
            }
        }
    }
    #pragma unroll
    for (int off = 32; off > 0; off >>= 1) lsum += __shfl_down(lsum, off, 64);
    if (lane == 0) wsum[wave] = lsum;
    __syncthreads();
    if (t == 0)
        atomicAdd(loss_acc, (double)((wsum[0] + wsum[1]) + (wsum[2] + wsum[3])));
}

// Rescue v11: RB_VEC 4 -> 8 (2 vectors staged per wave). Each cb row read now
// feeds EIGHT dot products: cb L2 traffic and per-code overhead (nj, address
// processing) halve again vs R13, and dt[8] gives 8 independent f64 chains.
// Codegen discipline unchanged (row loop unroll 1, q loop unroll 4, all
// arrays static-indexed; est ~90-110 VGPR, below spill). Loss: per-block slot
// write + stream-ordered finalize (zero same-address RMWs).
__global__ __launch_bounds__(256) void vq_rescue(
    const float* __restrict__ z, const float* __restrict__ cb,
    float* __restrict__ out,
    const int* __restrict__ counter, const int* __restrict__ worklist, int cap,
    double* __restrict__ lsum_ws)
{
    __shared__ float zsh[RB_VEC][DIM];           // 8 z rows (2 KB)
    __shared__ unsigned long long pls[4][RB_VEC];
    __shared__ double dsum[4];
    __shared__ int    nwl[RB_VEC];

    int count = *counter; if (count > cap) count = cap;
    const int t    = threadIdx.x;
    const int wave = t >> 6;
    const int lane = t & 63;

    double lloss = 0.0;                          // per-wave (lane0) accumulator

    for (int base = blockIdx.x * RB_VEC; base < count; base += gridDim.x * RB_VEC) {
        // ---- wave w stages z rows of vectors 2w, 2w+1 ----
        #pragma unroll
        for (int v = 0; v < 2; ++v) {
            const int vi = wave * 2 + v;
            const int i  = base + vi;
            int n = -1; float zval = 0.f;
            if (i < count) {
                n = worklist[i];
                const int bb = n >> 12, hw = n & 4095;
                zval = z[(size_t)bb * DHW + (size_t)lane * HW + hw];
            }
            zsh[vi][lane] = zval;
            if (lane == 0) nwl[vi] = n;
        }
        __syncthreads();                         // all 8 z rows visible

        // ---- ||z||^2 per vector (shuffle reduce; inactive vectors -> 0) ----
        double zn[RB_VEC];
        #pragma unroll
        for (int v = 0; v < RB_VEC; ++v) {
            const float zl = zsh[v][lane];
            double s = (double)zl * (double)zl;
            #pragma unroll
            for (int m = 1; m <= 32; m <<= 1) s += __shfl_xor(s, m, 64);
            zn[v] = s;
        }

        unsigned long long best[RB_VEC];
        #pragma unroll
        for (int v = 0; v < RB_VEC; ++v) best[v] = ~0ull;

        #pragma unroll 1
        for (int r = 0; r < 4; ++r) {
            const int k = wave * 256 + r * 64 + lane;
            const float4* cr = (const float4*)(cb + (size_t)k * DIM);
            double nj0 = 0.0, nj1 = 0.0;
            double dt[RB_VEC];
            #pragma unroll
            for (int v = 0; v < RB_VEC; ++v) dt[v] = 0.0;
            #pragma unroll 4
            for (int q = 0; q < 16; ++q) {
                const float4 c = cr[q];
                nj0 = fma((double)c.x, (double)c.x, nj0);
                nj1 = fma((double)c.y, (double)c.y, nj1);
                nj0 = fma((double)c.z, (double)c.z, nj0);
                nj1 = fma((double)c.w, (double)c.w, nj1);
                #pragma unroll
                for (int v = 0; v < RB_VEC; ++v) {
                    const float4 zv = *(const float4*)&zsh[v][q * 4];
                    dt[v] = fma((double)c.x, (double)zv.x, dt[v]);
                    dt[v] = fma((double)c.y, (double)zv.y, dt[v]);
                    dt[v] = fma((double)c.z, (double)zv.z, dt[v]);
                    dt[v] = fma((double)c.w, (double)zv.w, dt[v]);
                }
            }
            const double nj = nj0 + nj1;
            #pragma unroll
            for (int v = 0; v < RB_VEC; ++v) {
                const double p = fmax(fma(-2.0, dt[v], nj) + zn[v], 0.0);
                const unsigned long long q64 =
                    ((unsigned long long)__double_as_longlong(p) & ~1023ull)
                    | (unsigned long long)k;
                if (q64 < best[v]) best[v] = q64;
            }
        }

        // ---- cross-lane min per vector ----
        #pragma unroll
        for (int v = 0; v < RB_VEC; ++v) {
            unsigned long long b = best[v];
            #pragma unroll
            for (int m = 1; m <= 32; m <<= 1) {
                unsigned long long o = __shfl_xor(b, m, 64);
                if (o < b) b = o;
            }
            if (lane == 0) pls[wave][v] = b;
        }
        __syncthreads();                         // partials visible

        // ---- wave w finalizes vectors 2w, 2w+1 ----
        #pragma unroll
        for (int v = 0; v < 2; ++v) {
            const int vi = wave * 2 + v;
            const int n  = nwl[vi];
            if (n >= 0) {
                unsigned long long p0 = pls[0][vi], p1 = pls[1][vi];
                unsigned long long p2 = pls[2][vi], p3 = pls[3][vi];
                unsigned long long p = p0 < p1 ? p0 : p1;
                if (p2 < p) p = p2;
                if (p3 < p) p = p3;
                const int bk = (int)(p & 1023ull);
                const int bb = n >> 12, hw = n & 4095;
                out[(size_t)bb * DHW + (size_t)lane * HW + hw] = cb[(size_t)bk * DIM + lane];
                if (lane == 0)
                    lloss += __longlong_as_double((long long)(p & ~1023ull));
            }
        }
        __syncthreads();                         // zsh/pls safe to overwrite
    }

    if (lane == 0) dsum[wave] = lloss;
    __syncthreads();
    if (t == 0)
        lsum_ws[blockIdx.x] = (dsum[0] + dsum[1]) + (dsum[2] + dsum[3]);
}

// Stream-ordered finalize: reduce the RGRID block partials + main's loss_acc.
__global__ __launch_bounds__(256) void vq_finalize(
    const double* __restrict__ lsum_ws, const double* __restrict__ loss_acc,
    float* __restrict__ loss_out)
{
    __shared__ double ws4[4];
    const int t = threadIdx.x;
    double s = 0.0;
    for (int j = t; j < RGRID; j += 256) s += lsum_ws[j];
    #pragma unroll
    for (int m = 1; m <= 32; m <<= 1) s += __shfl_xor(s, m, 64);
    if ((t & 63) == 0) ws4[t >> 6] = s;
    __syncthreads();
    if (t == 0) {
        double total = *loss_acc + ((ws4[0] + ws4[1]) + (ws4[2] + ws4[3]));
        *loss_out = (float)(1.25 * total * (1.0 / (double)((long)N_VEC * DIM)));
    }
}

extern "C" void kernel_launch(void* const* d_in, const int* in_sizes, int n_in,
                              void* d_out, int out_size, void* d_ws, size_t ws_size,
                              hipStream_t stream) {
    const float* z  = (const float*)d_in[0];
    const float* cb = (const float*)d_in[1];
    float* out      = (float*)d_out;
    char*  ws       = (char*)d_ws;

    double* loss_acc = (double*)ws;
    int*    counter  = (int*)(ws + 8);
    int*    done     = (int*)(ws + 12);
    float*  norms    = (float*)(ws + 64);
    short*  ehg      = (short*)(ws + 8192);
    short*  elg      = (short*)(ws + 139264);
    int*    worklist = (int*)(ws + 270336);
    double* lsum_ws  = (double*)(ws + 303104);   // RGRID*8 = 8 KB, ends 311296

    int cap = WLCAP;
    long avail = ((long)ws_size - 270336) / 4;
    if (avail < cap) cap = (avail > 0) ? (int)avail : 0;

    vq_prep<<<dim3(KCODE / 16), dim3(256), 0, stream>>>(
        cb, norms, ehg, elg, loss_acc, counter, done);
    vq_main<<<dim3(N_VEC / BLK_ROWS), dim3(256), 0, stream>>>(
        z, cb, norms, ehg, elg, out, loss_acc, counter, worklist, cap);
    vq_rescue<<<dim3(RGRID), dim3(256), 0, stream>>>(
        z, cb, out, counter, worklist, cap, lsum_ws);
    vq_finalize<<<dim3(1), dim3(256), 0, stream>>>(
        lsum_ws, loss_acc, out + (out_size - 1));
}